// Round 1
// baseline (1918.242 us; speedup 1.0000x reference)
//
#include <hip/hip_runtime.h>

// GCNLayer: out = segment_sum(feature[src], dst) @ W^T + b
// Reordered as:  g = feature @ W^T  (ws);  out = b;  out[dst] += g[src]  (atomics)
// R1 baseline: establish correctness + measure atomic-scatter cost.

#define N_NODES 100000
#define N_EDGES 1600000
#define D 128

// ---------------- GEMM: g[n][o] = sum_k feat[n][k] * W[o][k] ----------------
__global__ __launch_bounds__(256) void gcn_gemm(const float* __restrict__ feat,
                                                const float* __restrict__ W,
                                                float* __restrict__ g, int nrows) {
    // Wt[k][o] = W[o][k]; +1 pad -> conflict-free staging writes and reads
    __shared__ float Wt[D][D + 1];
    for (int i = threadIdx.x; i < D * D; i += 256) {
        int o = i >> 7, k = i & (D - 1);
        Wt[k][o] = W[i];
    }
    __syncthreads();
    const int wave = threadIdx.x >> 6;
    const int lane = threadIdx.x & 63;
    for (int row = blockIdx.x * 4 + wave; row < nrows; row += gridDim.x * 4) {
        const float4* f4 = (const float4*)(feat + (size_t)row * D);
        float acc0 = 0.f, acc1 = 0.f;
#pragma unroll
        for (int k4 = 0; k4 < D / 4; ++k4) {
            const float4 fv = f4[k4];
            const int k = k4 * 4;
            acc0 = fmaf(fv.x, Wt[k + 0][lane], acc0);
            acc0 = fmaf(fv.y, Wt[k + 1][lane], acc0);
            acc0 = fmaf(fv.z, Wt[k + 2][lane], acc0);
            acc0 = fmaf(fv.w, Wt[k + 3][lane], acc0);
            acc1 = fmaf(fv.x, Wt[k + 0][lane + 64], acc1);
            acc1 = fmaf(fv.y, Wt[k + 1][lane + 64], acc1);
            acc1 = fmaf(fv.z, Wt[k + 2][lane + 64], acc1);
            acc1 = fmaf(fv.w, Wt[k + 3][lane + 64], acc1);
        }
        float* gr = g + (size_t)row * D;
        gr[lane] = acc0;
        gr[lane + 64] = acc1;
    }
}

// ---------------- out[n][o] = b[o] ----------------
__global__ __launch_bounds__(256) void gcn_init_out(const float* __restrict__ b,
                                                    float* __restrict__ out4n) {
    const size_t i = (size_t)blockIdx.x * 256 + threadIdx.x;  // float4 index
    const float4 bv = ((const float4*)b)[i & 31];             // (i*4)%128 / 4
    ((float4*)out4n)[i] = bv;
}

// ---------------- scatter: out[dst[e]] += g[src[e]] ----------------
// Index width is detected on-device: if data is int64 (values < 2^31), every
// odd 32-bit word is zero. For int32 random indices in [0,1e5) the probability
// of 4 odd words being zero is ~1e-20.
__device__ __forceinline__ bool idx_is_64(const void* p) {
    const unsigned* w = (const unsigned*)p;
    return (w[1] | w[3] | w[5] | w[7]) == 0u;
}
__device__ __forceinline__ int load_idx(const void* p, int e, bool is64) {
    return is64 ? (int)((const long long*)p)[e] : ((const int*)p)[e];
}

__global__ __launch_bounds__(256) void gcn_scatter(const void* __restrict__ src,
                                                   const void* __restrict__ dst,
                                                   const float* __restrict__ g,
                                                   float* __restrict__ out) {
    const int e = blockIdx.x * 4 + (threadIdx.x >> 6);
    if (e >= N_EDGES) return;
    const int lane = threadIdx.x & 63;
    const bool s64 = idx_is_64(src);
    const bool d64 = idx_is_64(dst);
    const int s = load_idx(src, e, s64);
    const int d = load_idx(dst, e, d64);
    const float2 v = ((const float2*)(g + (size_t)s * D))[lane];
    float* o = out + (size_t)d * D + (size_t)lane * 2;
    atomicAdd(o, v.x);
    atomicAdd(o + 1, v.y);
}

extern "C" void kernel_launch(void* const* d_in, const int* in_sizes, int n_in,
                              void* d_out, int out_size, void* d_ws, size_t ws_size,
                              hipStream_t stream) {
    const float* feat = (const float*)d_in[0];
    const void*  src  = d_in[1];
    const void*  dst  = d_in[2];
    const float* W    = (const float*)d_in[3];
    const float* b    = (const float*)d_in[4];
    float* out = (float*)d_out;
    float* g   = (float*)d_ws;  // N_NODES*D*4 = 51.2 MB scratch

    gcn_gemm<<<2048, 256, 0, stream>>>(feat, W, g, N_NODES);
    gcn_init_out<<<(N_NODES * D / 4) / 256, 256, 0, stream>>>(b, out);
    gcn_scatter<<<N_EDGES / 4, 256, 0, stream>>>(src, dst, g, out);
}

// Round 2
// 637.831 us; speedup vs baseline: 3.0074x; 3.0074x over previous
//
#include <hip/hip_runtime.h>

// GCNLayer: out = segment_sum(feature[src], dst) @ W^T + b
// R2: replace atomic scatter (2.07 GB HBM write traffic) with CSR-by-dst
// gather. h_neigh is materialized in d_out, then transformed in-place.
//
// ws layout (ints): off[100001] | cur[100000] (also histogram counts) |
//                   bsum[128] | ssrc[1600000]   -> 7.2 MB total

#define N_NODES 100000
#define N_EDGES 1600000
#define D 128
#define SCAN_NB 98  // ceil(100000/1024)

// ---- index width detection (reference declares int64; harness may give int32)
__device__ __forceinline__ bool idx_is_64(const void* p) {
    const unsigned* w = (const unsigned*)p;
    return (w[1] | w[3] | w[5] | w[7]) == 0u;  // odd words zero => int64
}
__device__ __forceinline__ int load_idx(const void* p, int e, bool is64) {
    return is64 ? (int)((const long long*)p)[e] : ((const int*)p)[e];
}

// ---- zero the histogram counters
__global__ __launch_bounds__(256) void gcn_zero(int* __restrict__ p, int n) {
    int i = blockIdx.x * 256 + threadIdx.x;
    if (i < n) p[i] = 0;
}

// ---- histogram of dst
__global__ __launch_bounds__(256) void gcn_hist(const void* __restrict__ dst,
                                                int* __restrict__ cnt) {
    int e = blockIdx.x * 256 + threadIdx.x;
    if (e >= N_EDGES) return;
    const bool d64 = idx_is_64(dst);
    atomicAdd(&cnt[load_idx(dst, e, d64)], 1);
}

// ---- scan step 1: per-block sums
__global__ __launch_bounds__(1024) void gcn_scan1(const int* __restrict__ cnt,
                                                  int* __restrict__ bsum) {
    __shared__ int sh[1024];
    int i = blockIdx.x * 1024 + threadIdx.x;
    sh[threadIdx.x] = (i < N_NODES) ? cnt[i] : 0;
    __syncthreads();
    for (int s = 512; s > 0; s >>= 1) {
        if (threadIdx.x < s) sh[threadIdx.x] += sh[threadIdx.x + s];
        __syncthreads();
    }
    if (threadIdx.x == 0) bsum[blockIdx.x] = sh[0];
}

// ---- scan step 2: exclusive scan of block sums (in place)
__global__ __launch_bounds__(128) void gcn_scan2(int* __restrict__ bsum) {
    __shared__ int sh[128];
    int t = threadIdx.x;
    int v = (t < SCAN_NB) ? bsum[t] : 0;
    sh[t] = v;
    __syncthreads();
    for (int s = 1; s < 128; s <<= 1) {
        int y = (t >= s) ? sh[t - s] : 0;
        __syncthreads();
        sh[t] += y;
        __syncthreads();
    }
    if (t < SCAN_NB) bsum[t] = sh[t] - v;  // exclusive
}

// ---- scan step 3: block exclusive scan + offset; write off[] and cur[]
// NOTE: cnt and cur alias (each thread reads its own cnt[i] before writing cur[i])
__global__ __launch_bounds__(1024) void gcn_scan3(const int* __restrict__ cnt,
                                                  const int* __restrict__ bsum,
                                                  int* __restrict__ off,
                                                  int* __restrict__ cur) {
    __shared__ int sh[1024];
    int t = threadIdx.x, i = blockIdx.x * 1024 + t;
    int v = (i < N_NODES) ? cnt[i] : 0;
    sh[t] = v;
    __syncthreads();
    for (int s = 1; s < 1024; s <<= 1) {
        int y = (t >= s) ? sh[t - s] : 0;
        __syncthreads();
        sh[t] += y;
        __syncthreads();
    }
    if (i < N_NODES) {
        int ex = bsum[blockIdx.x] + sh[t] - v;
        off[i] = ex;
        cur[i] = ex;
    }
    if (i == 0) off[N_NODES] = N_EDGES;  // sum of counts is exactly E
}

// ---- bucket edges by dst: ssrc holds src sorted by dst
__global__ __launch_bounds__(256) void gcn_bucket(const void* __restrict__ src,
                                                  const void* __restrict__ dst,
                                                  int* __restrict__ cur,
                                                  int* __restrict__ ssrc) {
    int e = blockIdx.x * 256 + threadIdx.x;
    if (e >= N_EDGES) return;
    const bool s64 = idx_is_64(src);
    const bool d64 = idx_is_64(dst);
    int s = load_idx(src, e, s64);
    int d = load_idx(dst, e, d64);
    int pos = atomicAdd(&cur[d], 1);
    ssrc[pos] = s;
}

// ---- aggregate: h[n] = sum_{j in CSR[n]} feature[ssrc[j]]   (one wave / node)
__global__ __launch_bounds__(256) void gcn_aggregate(const int* __restrict__ off,
                                                     const int* __restrict__ ssrc,
                                                     const float* __restrict__ feat,
                                                     float* __restrict__ h) {
    int n = blockIdx.x * 4 + (threadIdx.x >> 6);
    if (n >= N_NODES) return;
    const int lane = threadIdx.x & 63;
    int j = off[n];
    const int o1 = off[n + 1];
    float ax = 0.f, ay = 0.f;
    for (; j + 4 <= o1; j += 4) {
        int s0 = ssrc[j], s1 = ssrc[j + 1], s2 = ssrc[j + 2], s3 = ssrc[j + 3];
        float2 v0 = ((const float2*)(feat + (size_t)s0 * D))[lane];
        float2 v1 = ((const float2*)(feat + (size_t)s1 * D))[lane];
        float2 v2 = ((const float2*)(feat + (size_t)s2 * D))[lane];
        float2 v3 = ((const float2*)(feat + (size_t)s3 * D))[lane];
        ax += (v0.x + v1.x) + (v2.x + v3.x);
        ay += (v0.y + v1.y) + (v2.y + v3.y);
    }
    for (; j < o1; ++j) {
        int s = ssrc[j];
        float2 v = ((const float2*)(feat + (size_t)s * D))[lane];
        ax += v.x;
        ay += v.y;
    }
    float2 r;
    r.x = ax;
    r.y = ay;
    ((float2*)(h + (size_t)n * D))[lane] = r;
}

// ---- in-place row GEMM + bias: out[n] = h(out)[n] @ W^T + b
__global__ __launch_bounds__(256) void gcn_gemm_bias(const float* __restrict__ W,
                                                     const float* __restrict__ b,
                                                     float* __restrict__ out) {
    __shared__ float Wt[D][D + 1];   // Wt[k][o], pad -> conflict-free
    __shared__ float row[4][D];      // per-wave row broadcast buffer
    for (int i = threadIdx.x; i < D * D; i += 256) {
        int o = i >> 7, k = i & (D - 1);
        Wt[k][o] = W[i];
    }
    __syncthreads();
    const int wave = threadIdx.x >> 6;
    const int lane = threadIdx.x & 63;
    const float bias0 = b[lane], bias1 = b[lane + 64];
    const int n = blockIdx.x * 4 + wave;
    if (n >= N_NODES) return;
    float* orow = out + (size_t)n * D;
    // cooperative row load into per-wave LDS (wave-local: no barrier needed)
    float2 hv = ((const float2*)orow)[lane];
    ((float2*)row[wave])[lane] = hv;
    float acc0 = bias0, acc1 = bias1;
#pragma unroll 16
    for (int k = 0; k < D; ++k) {
        float f = row[wave][k];  // broadcast read
        acc0 = fmaf(f, Wt[k][lane], acc0);
        acc1 = fmaf(f, Wt[k][lane + 64], acc1);
    }
    orow[lane] = acc0;
    orow[lane + 64] = acc1;
}

extern "C" void kernel_launch(void* const* d_in, const int* in_sizes, int n_in,
                              void* d_out, int out_size, void* d_ws, size_t ws_size,
                              hipStream_t stream) {
    const float* feat = (const float*)d_in[0];
    const void*  src  = d_in[1];
    const void*  dst  = d_in[2];
    const float* W    = (const float*)d_in[3];
    const float* b    = (const float*)d_in[4];
    float* out = (float*)d_out;

    int* ws_i = (int*)d_ws;
    int* off  = ws_i;                 // 100001
    int* cur  = off + (N_NODES + 1);  // 100000 (doubles as histogram counts)
    int* bsum = cur + N_NODES;        // 128
    int* ssrc = bsum + 128;           // 1600000

    gcn_zero<<<(N_NODES + 255) / 256, 256, 0, stream>>>(cur, N_NODES);
    gcn_hist<<<N_EDGES / 256, 256, 0, stream>>>(dst, cur);
    gcn_scan1<<<SCAN_NB, 1024, 0, stream>>>(cur, bsum);
    gcn_scan2<<<1, 128, 0, stream>>>(bsum);
    gcn_scan3<<<SCAN_NB, 1024, 0, stream>>>(cur, bsum, off, cur);
    gcn_bucket<<<N_EDGES / 256, 256, 0, stream>>>(src, dst, cur, ssrc);
    gcn_aggregate<<<(N_NODES + 3) / 4, 256, 0, stream>>>(off, ssrc, feat, out);
    gcn_gemm_bias<<<(N_NODES + 3) / 4, 256, 0, stream>>>(W, b, out);
}

// Round 4
// 377.533 us; speedup vs baseline: 5.0810x; 1.6895x over previous
//
#include <hip/hip_runtime.h>

// GCNLayer: out = segment_sum(feature[src], dst) @ W^T + b
// R3 (resubmit; prior bench was an infra failure): bf16 gather + MFMA gemm.
//   fb = bf16(feature)                 (ws, 25.6 MB)
//   CSR by dst                         (ws, 7.2 MB)
//   h[n] = sum feature_bf16[ssrc]      -> packed bf16 into first 256B of out row n
//   out[n] = h[n] @ W^T_bf16 + b       (MFMA 16x16x32, in-place, barrier-ordered)

#define N_NODES 100000
#define N_EDGES 1600000
#define D 128
#define SCAN_NB 98  // ceil(100000/1024)

typedef float f32x4 __attribute__((ext_vector_type(4)));
typedef short bf16x8 __attribute__((ext_vector_type(8)));
typedef unsigned short u16x8 __attribute__((ext_vector_type(8)));
typedef unsigned int uint32;

// round-to-nearest-even fp32 -> bf16 (inputs are finite)
__device__ __forceinline__ uint32 f2bf(float f) {
    uint32 u = __float_as_uint(f);
    return (u + 0x7fffu + ((u >> 16) & 1u)) >> 16;
}

// ---- index width detection (reference declares int64; harness may give int32)
__device__ __forceinline__ bool idx_is_64(const void* p) {
    const unsigned* w = (const unsigned*)p;
    return (w[1] | w[3] | w[5] | w[7]) == 0u;  // odd words zero => int64
}
__device__ __forceinline__ int load_idx(const void* p, int e, bool is64) {
    return is64 ? (int)((const long long*)p)[e] : ((const int*)p)[e];
}

// ---- feature fp32 -> bf16
__global__ __launch_bounds__(256) void gcn_cvt_feat(const float* __restrict__ feat,
                                                    unsigned short* __restrict__ fb) {
    const size_t i = ((size_t)blockIdx.x * 256 + threadIdx.x) * 8;
    const float4 a = *((const float4*)(feat + i));
    const float4 c = *((const float4*)(feat + i + 4));
    u16x8 r;
    r[0] = (unsigned short)f2bf(a.x); r[1] = (unsigned short)f2bf(a.y);
    r[2] = (unsigned short)f2bf(a.z); r[3] = (unsigned short)f2bf(a.w);
    r[4] = (unsigned short)f2bf(c.x); r[5] = (unsigned short)f2bf(c.y);
    r[6] = (unsigned short)f2bf(c.z); r[7] = (unsigned short)f2bf(c.w);
    *((u16x8*)(fb + i)) = r;
}

// ---- zero histogram counters
__global__ __launch_bounds__(256) void gcn_zero(int* __restrict__ p, int n) {
    int i = blockIdx.x * 256 + threadIdx.x;
    if (i < n) p[i] = 0;
}

// ---- histogram of dst
__global__ __launch_bounds__(256) void gcn_hist(const void* __restrict__ dst,
                                                int* __restrict__ cnt) {
    int e = blockIdx.x * 256 + threadIdx.x;
    if (e >= N_EDGES) return;
    const bool d64 = idx_is_64(dst);
    atomicAdd(&cnt[load_idx(dst, e, d64)], 1);
}

// ---- scan step 1: per-block sums
__global__ __launch_bounds__(1024) void gcn_scan1(const int* __restrict__ cnt,
                                                  int* __restrict__ bsum) {
    __shared__ int sh[1024];
    int i = blockIdx.x * 1024 + threadIdx.x;
    sh[threadIdx.x] = (i < N_NODES) ? cnt[i] : 0;
    __syncthreads();
    for (int s = 512; s > 0; s >>= 1) {
        if (threadIdx.x < s) sh[threadIdx.x] += sh[threadIdx.x + s];
        __syncthreads();
    }
    if (threadIdx.x == 0) bsum[blockIdx.x] = sh[0];
}

// ---- scan step 2: exclusive scan of block sums (in place)
__global__ __launch_bounds__(128) void gcn_scan2(int* __restrict__ bsum) {
    __shared__ int sh[128];
    int t = threadIdx.x;
    int v = (t < SCAN_NB) ? bsum[t] : 0;
    sh[t] = v;
    __syncthreads();
    for (int s = 1; s < 128; s <<= 1) {
        int y = (t >= s) ? sh[t - s] : 0;
        __syncthreads();
        sh[t] += y;
        __syncthreads();
    }
    if (t < SCAN_NB) bsum[t] = sh[t] - v;  // exclusive
}

// ---- scan step 3: block exclusive scan + offset; write off[] and cur[]
__global__ __launch_bounds__(1024) void gcn_scan3(const int* __restrict__ cnt,
                                                  const int* __restrict__ bsum,
                                                  int* __restrict__ off,
                                                  int* __restrict__ cur) {
    __shared__ int sh[1024];
    int t = threadIdx.x, i = blockIdx.x * 1024 + t;
    int v = (i < N_NODES) ? cnt[i] : 0;
    sh[t] = v;
    __syncthreads();
    for (int s = 1; s < 1024; s <<= 1) {
        int y = (t >= s) ? sh[t - s] : 0;
        __syncthreads();
        sh[t] += y;
        __syncthreads();
    }
    if (i < N_NODES) {
        int ex = bsum[blockIdx.x] + sh[t] - v;
        off[i] = ex;
        cur[i] = ex;
    }
    if (i == 0) off[N_NODES] = N_EDGES;
}

// ---- bucket edges by dst: ssrc holds src sorted by dst
__global__ __launch_bounds__(256) void gcn_bucket(const void* __restrict__ src,
                                                  const void* __restrict__ dst,
                                                  int* __restrict__ cur,
                                                  int* __restrict__ ssrc) {
    int e = blockIdx.x * 256 + threadIdx.x;
    if (e >= N_EDGES) return;
    const bool s64 = idx_is_64(src);
    const bool d64 = idx_is_64(dst);
    int s = load_idx(src, e, s64);
    int d = load_idx(dst, e, d64);
    int pos = atomicAdd(&cur[d], 1);
    ssrc[pos] = s;
}

// ---- aggregate: h[n] = sum feature_bf16[ssrc[j]]; write bf16 into out row slot
__global__ __launch_bounds__(256) void gcn_aggregate(const int* __restrict__ off,
                                                     const int* __restrict__ ssrc,
                                                     const unsigned short* __restrict__ fb,
                                                     float* __restrict__ out) {
    const int n = blockIdx.x * 4 + (threadIdx.x >> 6);
    if (n >= N_NODES) return;
    const int lane = threadIdx.x & 63;
    int j = off[n];
    const int o1 = off[n + 1];
    float ax = 0.f, ay = 0.f;
    for (; j + 4 <= o1; j += 4) {
        const int s0 = ssrc[j], s1 = ssrc[j + 1], s2 = ssrc[j + 2], s3 = ssrc[j + 3];
        const uint32 v0 = *((const uint32*)(fb + (size_t)s0 * D) + lane);
        const uint32 v1 = *((const uint32*)(fb + (size_t)s1 * D) + lane);
        const uint32 v2 = *((const uint32*)(fb + (size_t)s2 * D) + lane);
        const uint32 v3 = *((const uint32*)(fb + (size_t)s3 * D) + lane);
        ax += __uint_as_float(v0 << 16) + __uint_as_float(v1 << 16) +
              __uint_as_float(v2 << 16) + __uint_as_float(v3 << 16);
        ay += __uint_as_float(v0 & 0xffff0000u) + __uint_as_float(v1 & 0xffff0000u) +
              __uint_as_float(v2 & 0xffff0000u) + __uint_as_float(v3 & 0xffff0000u);
    }
    for (; j < o1; ++j) {
        const uint32 v = *((const uint32*)(fb + (size_t)ssrc[j] * D) + lane);
        ax += __uint_as_float(v << 16);
        ay += __uint_as_float(v & 0xffff0000u);
    }
    // pack h[n][2*lane], h[n][2*lane+1] as bf16 pair into first 256B of out row n
    const uint32 packed = f2bf(ax) | (f2bf(ay) << 16);
    *((uint32*)(out + (size_t)n * D) + lane) = packed;
}

// ---- MFMA gemm + bias: out[n] = h_bf16(out)[n] @ W^T + b, in place
__global__ __launch_bounds__(256) void gcn_gemm_mfma(const float* __restrict__ W,
                                                     const float* __restrict__ b,
                                                     float* out) {
    const int wave = threadIdx.x >> 6;
    const int lane = threadIdx.x & 63;
    const int kg = lane >> 4;   // k-group 0..3
    const int ln = lane & 15;
    const int colbase = wave * 32;

    // B fragments: B[k][n] = W[n][k]; lane ln = output col, kg*8+j (+32t) = k
    bf16x8 Bf[2][4];
#pragma unroll
    for (int g = 0; g < 2; ++g) {
        const float* wrow = W + (size_t)(colbase + g * 16 + ln) * D + kg * 8;
#pragma unroll
        for (int t = 0; t < 4; ++t) {
            const float* wp = wrow + t * 32;
            bf16x8 bb;
#pragma unroll
            for (int j = 0; j < 8; ++j) bb[j] = (short)f2bf(wp[j]);
            Bf[g][t] = bb;
        }
    }
    const float bias0 = b[colbase + ln];
    const float bias1 = b[colbase + 16 + ln];

    const int R0 = blockIdx.x * 64;
#pragma unroll 1
    for (int c = 0; c < 4; ++c) {
        const int Rb = R0 + c * 16;
        int arow = Rb + ln;
        if (arow >= N_NODES) arow = N_NODES - 1;  // tail clamp (results discarded)
        const short* hrow = (const short*)(out + (size_t)arow * D);
        bf16x8 Af[4];
#pragma unroll
        for (int t = 0; t < 4; ++t)
            Af[t] = *((const bf16x8*)(hrow + t * 32 + kg * 8));
        f32x4 acc0 = {0.f, 0.f, 0.f, 0.f};
        f32x4 acc1 = {0.f, 0.f, 0.f, 0.f};
#pragma unroll
        for (int t = 0; t < 4; ++t) {
            acc0 = __builtin_amdgcn_mfma_f32_16x16x32_bf16(Af[t], Bf[0][t], acc0, 0, 0, 0);
            acc1 = __builtin_amdgcn_mfma_f32_16x16x32_bf16(Af[t], Bf[1][t], acc1, 0, 0, 0);
        }
        // all waves have consumed this chunk's h before anyone overwrites the rows
        __syncthreads();
#pragma unroll
        for (int j = 0; j < 4; ++j) {
            const int row = Rb + kg * 4 + j;
            if (row < N_NODES) {
                float* orow = out + (size_t)row * D + colbase;
                orow[ln] = acc0[j] + bias0;
                orow[16 + ln] = acc1[j] + bias1;
            }
        }
    }
}

extern "C" void kernel_launch(void* const* d_in, const int* in_sizes, int n_in,
                              void* d_out, int out_size, void* d_ws, size_t ws_size,
                              hipStream_t stream) {
    const float* feat = (const float*)d_in[0];
    const void*  src  = d_in[1];
    const void*  dst  = d_in[2];
    const float* W    = (const float*)d_in[3];
    const float* b    = (const float*)d_in[4];
    float* out = (float*)d_out;

    // ws: fb (bf16 feature, 25.6MB, 16B aligned) | off | cur | bsum | ssrc
    unsigned short* fb = (unsigned short*)d_ws;
    int* ws_i = (int*)(fb + (size_t)N_NODES * D);
    int* off  = ws_i;
    int* cur  = off + (N_NODES + 1);
    int* bsum = cur + N_NODES;
    int* ssrc = bsum + 128;

    gcn_cvt_feat<<<(N_NODES * D / 8) / 256, 256, 0, stream>>>(feat, fb);
    gcn_zero<<<(N_NODES + 255) / 256, 256, 0, stream>>>(cur, N_NODES);
    gcn_hist<<<N_EDGES / 256, 256, 0, stream>>>(dst, cur);
    gcn_scan1<<<SCAN_NB, 1024, 0, stream>>>(cur, bsum);
    gcn_scan2<<<1, 128, 0, stream>>>(bsum);
    gcn_scan3<<<SCAN_NB, 1024, 0, stream>>>(cur, bsum, off, cur);
    gcn_bucket<<<N_EDGES / 256, 256, 0, stream>>>(src, dst, cur, ssrc);
    gcn_aggregate<<<(N_NODES + 3) / 4, 256, 0, stream>>>(off, ssrc, fb, out);
    gcn_gemm_mfma<<<(N_NODES + 63) / 64, 256, 0, stream>>>(W, b, out);
}

// Round 5
// 329.709 us; speedup vs baseline: 5.8180x; 1.1450x over previous
//
#include <hip/hip_runtime.h>

// GCNLayer: out = segment_sum(feature[src], dst) @ W^T + b
// R5: replace single-pass bucket (105 MB scattered-write amplification) with
// two-pass partition: coarse counting-sort into 391 buckets (coalesced run
// writes) + per-bucket L2-local scatter to final CSR order.

#define N_NODES 100000
#define N_EDGES 1600000
#define D 128
#define SCAN_NB 98   // ceil(100000/1024)
#define NBK 391      // ceil(100000/256) coarse buckets (256 nodes each)
#define CHUNK 4096   // edges per partition block

typedef float f32x4 __attribute__((ext_vector_type(4)));
typedef short bf16x8 __attribute__((ext_vector_type(8)));
typedef unsigned short u16x8 __attribute__((ext_vector_type(8)));
typedef unsigned int uint32;

// round-to-nearest-even fp32 -> bf16 (inputs are finite)
__device__ __forceinline__ uint32 f2bf(float f) {
    uint32 u = __float_as_uint(f);
    return (u + 0x7fffu + ((u >> 16) & 1u)) >> 16;
}

// ---- index width detection (reference declares int64; harness may give int32)
__device__ __forceinline__ bool idx_is_64(const void* p) {
    const unsigned* w = (const unsigned*)p;
    return (w[1] | w[3] | w[5] | w[7]) == 0u;  // odd words zero => int64
}
__device__ __forceinline__ int load_idx(const void* p, int e, bool is64) {
    return is64 ? (int)((const long long*)p)[e] : ((const int*)p)[e];
}

// ---- feature fp32 -> bf16
__global__ __launch_bounds__(256) void gcn_cvt_feat(const float* __restrict__ feat,
                                                    unsigned short* __restrict__ fb) {
    const size_t i = ((size_t)blockIdx.x * 256 + threadIdx.x) * 8;
    const float4 a = *((const float4*)(feat + i));
    const float4 c = *((const float4*)(feat + i + 4));
    u16x8 r;
    r[0] = (unsigned short)f2bf(a.x); r[1] = (unsigned short)f2bf(a.y);
    r[2] = (unsigned short)f2bf(a.z); r[3] = (unsigned short)f2bf(a.w);
    r[4] = (unsigned short)f2bf(c.x); r[5] = (unsigned short)f2bf(c.y);
    r[6] = (unsigned short)f2bf(c.z); r[7] = (unsigned short)f2bf(c.w);
    *((u16x8*)(fb + i)) = r;
}

// ---- zero histogram counters
__global__ __launch_bounds__(256) void gcn_zero(int* __restrict__ p, int n) {
    int i = blockIdx.x * 256 + threadIdx.x;
    if (i < n) p[i] = 0;
}

// ---- histogram of dst
__global__ __launch_bounds__(256) void gcn_hist(const void* __restrict__ dst,
                                                int* __restrict__ cnt) {
    int e = blockIdx.x * 256 + threadIdx.x;
    if (e >= N_EDGES) return;
    const bool d64 = idx_is_64(dst);
    atomicAdd(&cnt[load_idx(dst, e, d64)], 1);
}

// ---- scan step 1: per-block sums
__global__ __launch_bounds__(1024) void gcn_scan1(const int* __restrict__ cnt,
                                                  int* __restrict__ bsum) {
    __shared__ int sh[1024];
    int i = blockIdx.x * 1024 + threadIdx.x;
    sh[threadIdx.x] = (i < N_NODES) ? cnt[i] : 0;
    __syncthreads();
    for (int s = 512; s > 0; s >>= 1) {
        if (threadIdx.x < s) sh[threadIdx.x] += sh[threadIdx.x + s];
        __syncthreads();
    }
    if (threadIdx.x == 0) bsum[blockIdx.x] = sh[0];
}

// ---- scan step 2: exclusive scan of block sums (in place)
__global__ __launch_bounds__(128) void gcn_scan2(int* __restrict__ bsum) {
    __shared__ int sh[128];
    int t = threadIdx.x;
    int v = (t < SCAN_NB) ? bsum[t] : 0;
    sh[t] = v;
    __syncthreads();
    for (int s = 1; s < 128; s <<= 1) {
        int y = (t >= s) ? sh[t - s] : 0;
        __syncthreads();
        sh[t] += y;
        __syncthreads();
    }
    if (t < SCAN_NB) bsum[t] = sh[t] - v;  // exclusive
}

// ---- scan step 3: block exclusive scan + offset; write off[], cur[], bcur[]
__global__ __launch_bounds__(1024) void gcn_scan3(const int* __restrict__ cnt,
                                                  const int* __restrict__ bsum,
                                                  int* __restrict__ off,
                                                  int* __restrict__ cur,
                                                  int* __restrict__ bcur) {
    __shared__ int sh[1024];
    int t = threadIdx.x, i = blockIdx.x * 1024 + t;
    int v = (i < N_NODES) ? cnt[i] : 0;
    sh[t] = v;
    __syncthreads();
    for (int s = 1; s < 1024; s <<= 1) {
        int y = (t >= s) ? sh[t - s] : 0;
        __syncthreads();
        sh[t] += y;
        __syncthreads();
    }
    if (i < N_NODES) {
        int ex = bsum[blockIdx.x] + sh[t] - v;
        off[i] = ex;
        cur[i] = ex;
        if ((i & 255) == 0) bcur[i >> 8] = ex;  // bucket base = off[bk<<8]
    }
    if (i == 0) off[N_NODES] = N_EDGES;
}

// ---- partition pass 1: block counting-sort into NBK coarse buckets
__global__ __launch_bounds__(512) void gcn_part(const void* __restrict__ src,
                                                const void* __restrict__ dst,
                                                int* __restrict__ bcur,
                                                uint32* __restrict__ ebuf) {
    __shared__ int cnt[NBK];        // counts -> scatter cursors
    __shared__ int scanbuf[512];
    __shared__ int baseL[NBK];
    __shared__ int gbase[NBK];
    __shared__ uint32 pairs[CHUNK];
    __shared__ unsigned short pbk[CHUNK];
    const int t = threadIdx.x;
    for (int i = t; i < NBK; i += 512) cnt[i] = 0;
    __syncthreads();
    const bool s64 = idx_is_64(src);
    const bool d64 = idx_is_64(dst);
    const int e0 = blockIdx.x * CHUNK;
    const int nvalid = (N_EDGES - e0 < CHUNK) ? (N_EDGES - e0) : CHUNK;
    uint32 v[CHUNK / 512];
    int bkr[CHUNK / 512];
#pragma unroll
    for (int i = 0; i < CHUNK / 512; ++i) {
        const int e = e0 + i * 512 + t;
        if (e < N_EDGES) {
            const int s = load_idx(src, e, s64);
            const int d = load_idx(dst, e, d64);
            const int bk = d >> 8;
            v[i] = ((uint32)s << 8) | (uint32)(d & 255);
            bkr[i] = bk;
            atomicAdd(&cnt[bk], 1);
        } else {
            bkr[i] = -1;
        }
    }
    __syncthreads();
    // exclusive scan of cnt -> baseL; reserve global runs; cnt becomes cursor
    const int c = (t < NBK) ? cnt[t] : 0;
    scanbuf[t] = c;
    __syncthreads();
    for (int s = 1; s < 512; s <<= 1) {
        const int y = (t >= s) ? scanbuf[t - s] : 0;
        __syncthreads();
        scanbuf[t] += y;
        __syncthreads();
    }
    if (t < NBK) {
        const int ex = scanbuf[t] - c;
        baseL[t] = ex;
        cnt[t] = ex;
        gbase[t] = c ? atomicAdd(&bcur[t], c) : 0;
    }
    __syncthreads();
#pragma unroll
    for (int i = 0; i < CHUNK / 512; ++i) {
        if (bkr[i] >= 0) {
            const int idx = atomicAdd(&cnt[bkr[i]], 1);
            pairs[idx] = v[i];
            pbk[idx] = (unsigned short)bkr[i];
        }
    }
    __syncthreads();
    // coalesced run copy-out: consecutive i in a bucket -> consecutive global
    for (int i = t; i < nvalid; i += 512) {
        const int bk = pbk[i];
        ebuf[gbase[bk] + (i - baseL[bk])] = pairs[i];
    }
}

// ---- partition pass 2: per-bucket L2-local scatter to exact CSR order
__global__ __launch_bounds__(256) void gcn_scatter2(const int* __restrict__ off,
                                                    const uint32* __restrict__ ebuf,
                                                    int* __restrict__ cur,
                                                    int* __restrict__ ssrc) {
    const int bk = blockIdx.x;
    const int nb0 = bk << 8;
    int nb1 = nb0 + 256;
    if (nb1 > N_NODES) nb1 = N_NODES;
    const int lo = off[nb0];
    const int hi = off[nb1];
    for (int i = lo + threadIdx.x; i < hi; i += 256) {
        const uint32 v = ebuf[i];
        const int d = nb0 | (int)(v & 255u);
        const int pos = atomicAdd(&cur[d], 1);
        ssrc[pos] = (int)(v >> 8);
    }
}

// ---- aggregate: h[n] = sum feature_bf16[ssrc[j]]; write bf16 into out row slot
__global__ __launch_bounds__(256) void gcn_aggregate(const int* __restrict__ off,
                                                     const int* __restrict__ ssrc,
                                                     const unsigned short* __restrict__ fb,
                                                     float* __restrict__ out) {
    const int n = blockIdx.x * 4 + (threadIdx.x >> 6);
    if (n >= N_NODES) return;
    const int lane = threadIdx.x & 63;
    int j = off[n];
    const int o1 = off[n + 1];
    float ax = 0.f, ay = 0.f;
    for (; j + 4 <= o1; j += 4) {
        const int s0 = ssrc[j], s1 = ssrc[j + 1], s2 = ssrc[j + 2], s3 = ssrc[j + 3];
        const uint32 v0 = *((const uint32*)(fb + (size_t)s0 * D) + lane);
        const uint32 v1 = *((const uint32*)(fb + (size_t)s1 * D) + lane);
        const uint32 v2 = *((const uint32*)(fb + (size_t)s2 * D) + lane);
        const uint32 v3 = *((const uint32*)(fb + (size_t)s3 * D) + lane);
        ax += __uint_as_float(v0 << 16) + __uint_as_float(v1 << 16) +
              __uint_as_float(v2 << 16) + __uint_as_float(v3 << 16);
        ay += __uint_as_float(v0 & 0xffff0000u) + __uint_as_float(v1 & 0xffff0000u) +
              __uint_as_float(v2 & 0xffff0000u) + __uint_as_float(v3 & 0xffff0000u);
    }
    for (; j < o1; ++j) {
        const uint32 v = *((const uint32*)(fb + (size_t)ssrc[j] * D) + lane);
        ax += __uint_as_float(v << 16);
        ay += __uint_as_float(v & 0xffff0000u);
    }
    const uint32 packed = f2bf(ax) | (f2bf(ay) << 16);
    *((uint32*)(out + (size_t)n * D) + lane) = packed;
}

// ---- MFMA gemm + bias: out[n] = h_bf16(out)[n] @ W^T + b, in place
__global__ __launch_bounds__(256) void gcn_gemm_mfma(const float* __restrict__ W,
                                                     const float* __restrict__ b,
                                                     float* out) {
    const int wave = threadIdx.x >> 6;
    const int lane = threadIdx.x & 63;
    const int kg = lane >> 4;   // k-group 0..3
    const int ln = lane & 15;
    const int colbase = wave * 32;

    bf16x8 Bf[2][4];
#pragma unroll
    for (int g = 0; g < 2; ++g) {
        const float* wrow = W + (size_t)(colbase + g * 16 + ln) * D + kg * 8;
#pragma unroll
        for (int t = 0; t < 4; ++t) {
            const float* wp = wrow + t * 32;
            bf16x8 bb;
#pragma unroll
            for (int j = 0; j < 8; ++j) bb[j] = (short)f2bf(wp[j]);
            Bf[g][t] = bb;
        }
    }
    const float bias0 = b[colbase + ln];
    const float bias1 = b[colbase + 16 + ln];

    const int R0 = blockIdx.x * 64;
#pragma unroll 1
    for (int c = 0; c < 4; ++c) {
        const int Rb = R0 + c * 16;
        int arow = Rb + ln;
        if (arow >= N_NODES) arow = N_NODES - 1;  // tail clamp (results discarded)
        const short* hrow = (const short*)(out + (size_t)arow * D);
        bf16x8 Af[4];
#pragma unroll
        for (int t = 0; t < 4; ++t)
            Af[t] = *((const bf16x8*)(hrow + t * 32 + kg * 8));
        f32x4 acc0 = {0.f, 0.f, 0.f, 0.f};
        f32x4 acc1 = {0.f, 0.f, 0.f, 0.f};
#pragma unroll
        for (int t = 0; t < 4; ++t) {
            acc0 = __builtin_amdgcn_mfma_f32_16x16x32_bf16(Af[t], Bf[0][t], acc0, 0, 0, 0);
            acc1 = __builtin_amdgcn_mfma_f32_16x16x32_bf16(Af[t], Bf[1][t], acc1, 0, 0, 0);
        }
        __syncthreads();  // all waves consumed chunk's h before overwrite
#pragma unroll
        for (int j = 0; j < 4; ++j) {
            const int row = Rb + kg * 4 + j;
            if (row < N_NODES) {
                float* orow = out + (size_t)row * D + colbase;
                orow[ln] = acc0[j] + bias0;
                orow[16 + ln] = acc1[j] + bias1;
            }
        }
    }
}

extern "C" void kernel_launch(void* const* d_in, const int* in_sizes, int n_in,
                              void* d_out, int out_size, void* d_ws, size_t ws_size,
                              hipStream_t stream) {
    const float* feat = (const float*)d_in[0];
    const void*  src  = d_in[1];
    const void*  dst  = d_in[2];
    const float* W    = (const float*)d_in[3];
    const float* b    = (const float*)d_in[4];
    float* out = (float*)d_out;

    // ws: fb bf16[12.8M] | off[100001] | cur[100000] | bsum[128] | bcur[392]
    //     | ssrc[1.6M] | ebuf[1.6M]  ~= 39.2 MB
    unsigned short* fb = (unsigned short*)d_ws;
    int* ws_i = (int*)(fb + (size_t)N_NODES * D);
    int* off  = ws_i;
    int* cur  = off + (N_NODES + 1);
    int* bsum = cur + N_NODES;
    int* bcur = bsum + 128;
    int* ssrc = bcur + 392;
    uint32* ebuf = (uint32*)(ssrc + N_EDGES);

    gcn_cvt_feat<<<(N_NODES * D / 8) / 256, 256, 0, stream>>>(feat, fb);
    gcn_zero<<<(N_NODES + 255) / 256, 256, 0, stream>>>(cur, N_NODES);
    gcn_hist<<<N_EDGES / 256, 256, 0, stream>>>(dst, cur);
    gcn_scan1<<<SCAN_NB, 1024, 0, stream>>>(cur, bsum);
    gcn_scan2<<<1, 128, 0, stream>>>(bsum);
    gcn_scan3<<<SCAN_NB, 1024, 0, stream>>>(cur, bsum, off, cur, bcur);
    gcn_part<<<(N_EDGES + CHUNK - 1) / CHUNK, 512, 0, stream>>>(src, dst, bcur, ebuf);
    gcn_scatter2<<<NBK, 256, 0, stream>>>(off, ebuf, cur, ssrc);
    gcn_aggregate<<<(N_NODES + 3) / 4, 256, 0, stream>>>(off, ssrc, fb, out);
    gcn_gemm_mfma<<<(N_NODES + 63) / 64, 256, 0, stream>>>(W, b, out);
}